// Round 16
// baseline (205.945 us; speedup 1.0000x reference)
//
#include <hip/hip_runtime.h>

// EncoderTreeRNN — R16 (= R15 resubmit after infra failure): wave-specialized tree kernel
// with REGISTER-RESIDENT weights.
// 768 thr = 12 waves = (g,cg), g in {z,r,h}, cg in 0..3. Each wave preloads its 16 B-frags
// (64 VGPR) once per block -> ZERO in-loop weight loads (the invariant stall of R8-R14).
// Pipeline over tiles: z/r-waves gemm+EW tile t, h-waves gemm+epilogue tile t-1.
// Tree (word=0): z=sigm(hl Uzl+hr Uzr+bz), r=sigm(hl Url+hr Urr+br),
//                h~=tanh((r*hl)Uhl+(r*hr)Uhr+bh), out=z*(hl+hr)+(1-z)*h~ = c1 + c2*h~
// with c1=z*s, c2=1-z computed by z-waves into CB; RH=r(.)h by r-waves.
// K interleaved (k'=2j -> hl[j], 2j+1 -> hr[j]); U rows permuted to match (wprep).
// U frag (32x32): Uf[((cg*16+ks)*64+l)*8+j] = U'[ks*16+(l>>5)*8+j][cg*32+(l&31)].
// C/D: col=lane&31, row=(reg&3)+8*(reg>>2)+4*(lane>>5).
// Inter-level h buffer: pair-interleaved u32 {h[2p][c],h[2p+1][c]} at [p*128+c].

typedef _Float16 half_t;
typedef __attribute__((ext_vector_type(2))) _Float16 f16x2;
typedef __attribute__((ext_vector_type(8))) _Float16 f16x8;
typedef __attribute__((ext_vector_type(4))) float f32x4;
typedef __attribute__((ext_vector_type(16))) float f32x16;

#define NTOK 262144
#define NB 4096
#define NV 100000

__device__ __forceinline__ float sigm(float x){
  float e = __expf(-x);
  return __builtin_amdgcn_rcpf(1.0f + e);
}
__device__ __forceinline__ float tanh_(float x){
  float e = __expf(2.f*x);
  float r = __builtin_amdgcn_rcpf(1.0f + e);
  return __builtin_fmaf(-2.0f, r, 1.0f);
}

__global__ void bias_k(const float* bWz,const float* bUzl,const float* bUzr,
                       const float* bWr,const float* bUrl,const float* bUrr,
                       const float* bWh,const float* bUhl,const float* bUhr, float* bc){
  int j = threadIdx.x;
  if (j < 128)      bc[j] = bWz[j]+bUzl[j]+bUzr[j];
  else if (j < 256){ int i=j-128; bc[j] = bWr[i]+bUrl[i]+bUrr[i]; }
  else if (j < 384){ int i=j-256; bc[j] = bWh[i]+bUhl[i]+bUhr[i]; }
}

// W (16x16 frag, K=128): Wf[((w*4+ks)*64+l)*8+j] = W[ks*32+(l>>4)*8+j][w*16+(l&15)]
// U (32x32 frag, K=256 interleaved): see header.
__global__ __launch_bounds__(256) void wprep_k(
    const float* Wz, const float* Wh,
    const float* Uzl,const float* Uzr,const float* Url,const float* Urr,
    const float* Uhl,const float* Uhr, half_t* wb){
  int idx = blockIdx.x*256 + threadIdx.x;           // 131072 total
  if (idx < 32768){                                  // Wz_f, Wh_f (16x16 layout)
    const float* W = (idx < 16384) ? Wz : Wh;
    int t = idx & 16383;
    int w = t >> 11, ks = (t >> 9) & 3, l = (t >> 3) & 63, j = t & 7;
    int n = w*16 + (l & 15);
    int k = ks*32 + ((l >> 4) << 3) + j;
    wb[idx] = (half_t)W[k*128 + n];
  } else {                                           // Uz_f, Ur_f, Uh_f (32x32 layout)
    int t = idx - 32768;
    int mat = t >> 15;                               // 0=z,1=r,2=h
    t &= 32767;
    int cg = t >> 13, ks = (t >> 9) & 15, l = (t >> 3) & 63, j = t & 7;
    int n = cg*32 + (l & 31);
    int kp = ks*16 + ((l >> 5) << 3) + j;            // 0..255 interleaved
    int k = kp >> 1;
    const float* U;
    if (mat == 0) U = (kp & 1) ? Uzr : Uzl;
    else if (mat == 1) U = (kp & 1) ? Urr : Url;
    else U = (kp & 1) ? Uhr : Uhl;
    wb[idx] = (half_t)U[k*128 + n];
  }
}

// Vocab table (16x16 path): t1[v] = (1-z)*tanh(xWh+bh), z=sigm(xWz+bz). Sequential rows.
template<int MT>
__global__ __launch_bounds__(512, 8) void h1tab_k(
    const float* __restrict__ emb,
    const half_t* __restrict__ Wz_f, const half_t* __restrict__ Wh_f,
    const float* __restrict__ bc, half_t* __restrict__ t1)
{
  __shared__ __align__(16) _Float16 xs[MT*16][136];
  const int tid = threadIdx.x;
  const int m0  = blockIdx.x*(MT*16);
  #pragma unroll
  for (int it = 0; it < MT; it++){
    int idx = it*512 + tid;
    int m = idx >> 5, c = idx & 31;
    int row = m0 + m; if (row >= NV) row = 0;
    float4 v = ((const float4*)(emb + (size_t)row*128))[c];
    union { half_t h[4]; ushort4 u; } p;
    p.h[0]=(half_t)v.x; p.h[1]=(half_t)v.y; p.h[2]=(half_t)v.z; p.h[3]=(half_t)v.w;
    *(ushort4*)&xs[m][c*4] = p.u;
  }
  __syncthreads();
  const int w = tid>>6, l = tid&63;
  const int lr = l&15, lk = (l>>4)*8, lq = (l>>4)*4;
  const int col = w*16 + lr;

  f32x4 zacc[MT] = {}; f32x4 hacc[MT] = {};
  const half_t* wzp = Wz_f + ((w*4)*64 + l)*8;
  const half_t* whp = Wh_f + ((w*4)*64 + l)*8;
  #pragma unroll
  for (int ks=0; ks<4; ks++){
    f16x8 bz = *(const f16x8*)(wzp + ks*512);
    f16x8 bh = *(const f16x8*)(whp + ks*512);
    #pragma unroll
    for (int mt=0; mt<MT; mt++){
      f16x8 a = *(const f16x8*)&xs[mt*16 + lr][ks*32 + lk];
      zacc[mt] = __builtin_amdgcn_mfma_f32_16x16x32_f16(a, bz, zacc[mt],0,0,0);
      hacc[mt] = __builtin_amdgcn_mfma_f32_16x16x32_f16(a, bh, hacc[mt],0,0,0);
    }
  }
  const float bzv = bc[col], bhv = bc[256+col];
  #pragma unroll
  for (int mt=0; mt<MT; mt++){
    #pragma unroll
    for (int q=0; q<4; q++){
      int row = m0 + mt*16 + lq + q;
      if (row < NV){
        float z  = sigm(zacc[mt][q] + bzv);
        float ht = tanh_(hacc[mt][q] + bhv);
        t1[(size_t)row*128 + col] = (half_t)((1.f-z)*ht);
      }
    }
  }
}

// Wave-specialized tree level. 768 thr = 12 waves (g in {0:z,1:r,2:h}) x cg.
// Block processes tpb tiles of 32 rows, pipelined: zr on tile i, h on tile i-1.
template<int GATHER, int LAST>
__global__ __launch_bounds__(768, 3) void tree_k(
    const half_t* __restrict__ hin, const int* __restrict__ tokens,
    uint* __restrict__ hout32, float* __restrict__ outf,
    const half_t* __restrict__ Uz_f, const half_t* __restrict__ Ur_f, const half_t* __restrict__ Uh_f,
    const float* __restrict__ bc, int tpb)
{
  __shared__ __align__(16) _Float16 A [2][32][264];   // raw {hl,hr} interleaved
  __shared__ __align__(16) _Float16 RH[2][32][264];   // r(.)h interleaved
  __shared__ uint CB[2][32][128];                     // packed {c1,c2} f16x2
  const int tid = threadIdx.x;
  const int wid = tid >> 6, l = tid & 63;
  const int g = wid >> 2, cg = wid & 3;
  const int lc = l & 31, hi = l >> 5, lk8 = hi*8;
  const int col = cg*32 + lc;
  const float bias = bc[g*128 + col];

  // --- preload this wave's B fragments: 16 x f16x8 = 64 VGPR, persistent ---
  const half_t* Uf = (g==0) ? Uz_f : (g==1) ? Ur_f : Uh_f;
  f16x8 B[16];
  #pragma unroll
  for (int ks = 0; ks < 16; ks++)
    B[ks] = *(const f16x8*)(Uf + ((cg*16+ks)*64 + l)*8);

  const int t0 = blockIdx.x * tpb;
  uint4 stg[2];

  auto stage_load = [&](int tg){
    #pragma unroll
    for (int it = 0; it < 2; it++){
      int idx = it*768 + tid;
      if (idx < 1024){
        int m = idx >> 5, c = idx & 31;
        if (GATHER){
          int gm = tg*32 + m;
          int tl = tokens[2*gm], tr = tokens[2*gm+1];
          uint2 a2 = *(const uint2*)(hin + (size_t)tl*128 + c*4);
          uint2 b2 = *(const uint2*)(hin + (size_t)tr*128 + c*4);
          stg[it].x = (a2.x & 0xFFFFu) | (b2.x << 16);
          stg[it].y = (a2.x >> 16)     | (b2.x & 0xFFFF0000u);
          stg[it].z = (a2.y & 0xFFFFu) | (b2.y << 16);
          stg[it].w = (a2.y >> 16)     | (b2.y & 0xFFFF0000u);
        } else {
          stg[it] = ((const uint4*)((const uint*)hin + (size_t)tg*32*128))[idx];
        }
      }
    }
  };
  auto stage_write = [&](int buf){
    #pragma unroll
    for (int it = 0; it < 2; it++){
      int idx = it*768 + tid;
      if (idx < 1024){
        int m = idx >> 5, c = idx & 31;
        *(uint4*)&A[buf][m][c*8] = stg[it];
      }
    }
  };
  auto gemm = [&](const _Float16 (*src)[264], f32x16& acc){
    #pragma unroll
    for (int ks = 0; ks < 16; ks++){
      f16x8 a = *(const f16x8*)&src[lc][ks*16 + lk8];
      acc = __builtin_amdgcn_mfma_f32_32x32x16_f16(a, B[ks], acc,0,0,0);
    }
  };
  auto ew_z = [&](int buf, const f32x16& acc){
    #pragma unroll
    for (int r = 0; r < 16; r++){
      int row = (r&3) + 8*(r>>2) + 4*hi;
      union { uint u; f16x2 h2; } io;
      io.u = *(uint*)&A[buf][row][2*col];
      float z = sigm(acc[r] + bias);
      float s = (float)io.h2[0] + (float)io.h2[1];
      union { uint u; f16x2 h2; } cb;
      cb.h2[0] = (half_t)(z * s);
      cb.h2[1] = (half_t)(1.0f - z);
      CB[buf][row][col] = cb.u;
    }
  };
  auto ew_r = [&](int buf, const f32x16& acc){
    #pragma unroll
    for (int r = 0; r < 16; r++){
      int row = (r&3) + 8*(r>>2) + 4*hi;
      union { uint u; f16x2 h2; } io;
      io.u = *(uint*)&A[buf][row][2*col];
      float rv = sigm(acc[r] + bias);
      half_t rh = (half_t)rv;
      f16x2 r2; r2[0]=rh; r2[1]=rh;
      io.h2 = io.h2 * r2;                 // v_pk_mul_f16
      *(uint*)&RH[buf][row][2*col] = io.u;
    }
  };
  auto epilogue = [&](int tg, int buf, const f32x16& acc){
    #pragma unroll
    for (int p = 0; p < 8; p++){
      int r0 = 2*p;
      int row0 = 2*(p&1) + 8*(p>>1) + 4*hi;   // rows row0, row0+1
      float o[2];
      #pragma unroll
      for (int e = 0; e < 2; e++){
        union { uint u; f16x2 h2; } cb;
        cb.u = CB[buf][row0+e][col];
        float ht = tanh_(acc[r0+e] + bias);
        o[e] = __builtin_fmaf((float)cb.h2[1], ht, (float)cb.h2[0]);
      }
      if (LAST){
        outf[(size_t)(tg*32 + row0)*128 + col]     = o[0];
        outf[(size_t)(tg*32 + row0 + 1)*128 + col] = o[1];
      } else {
        union { uint u; f16x2 h2; } pk;
        pk.h2[0] = (half_t)o[0]; pk.h2[1] = (half_t)o[1];
        hout32[(size_t)((tg*32 + row0) >> 1)*128 + col] = pk.u;
      }
    }
  };

  // ---- pipeline ----
  stage_load(t0);
  stage_write(0);
  __syncthreads();

  f32x16 acc;
  for (int i = 0; i < tpb; i++){
    int buf = i & 1;
    if (i+1 < tpb) stage_load(t0+i+1);
    acc = f32x16{};
    if (g < 2){
      gemm(A[buf], acc);
    } else if (i > 0){
      gemm(RH[buf^1], acc);
      epilogue(t0+i-1, buf^1, acc);
    }
    __syncthreads();
    if (g == 0)      ew_z(buf, acc);
    else if (g == 1) ew_r(buf, acc);
    if (i+1 < tpb) stage_write(buf^1);
    __syncthreads();
  }
  // drain: h for last tile
  if (g == 2){
    int buf = (tpb-1) & 1;
    acc = f32x16{};
    gemm(RH[buf], acc);
    epilogue(t0+tpb-1, buf, acc);
  }
}

extern "C" void kernel_launch(void* const* d_in, const int* in_sizes, int n_in,
                              void* d_out, int out_size, void* d_ws, size_t ws_size,
                              hipStream_t stream) {
  const int*   tokens = (const int*)  d_in[0];
  const float* emb    = (const float*)d_in[1];
  const float* Wz  = (const float*)d_in[2];  const float* bWz  = (const float*)d_in[3];
  const float* Uzl = (const float*)d_in[4];  const float* bUzl = (const float*)d_in[5];
  const float* Uzr = (const float*)d_in[6];  const float* bUzr = (const float*)d_in[7];
  const float* Wr  = (const float*)d_in[8];  const float* bWr  = (const float*)d_in[9];
  const float* Url = (const float*)d_in[10]; const float* bUrl = (const float*)d_in[11];
  const float* Urr = (const float*)d_in[12]; const float* bUrr = (const float*)d_in[13];
  const float* Wh  = (const float*)d_in[14]; const float* bWh  = (const float*)d_in[15];
  const float* Uhl = (const float*)d_in[16]; const float* bUhl = (const float*)d_in[17];
  const float* Uhr = (const float*)d_in[18]; const float* bUhr = (const float*)d_in[19];

  float*  bc = (float*)d_ws;
  half_t* wb = (half_t*)((char*)d_ws + 4096);
  half_t* Wz_f = wb;
  half_t* Wh_f = wb + 16384;
  half_t* Uz_f = wb + 32768;
  half_t* Ur_f = wb + 65536;
  half_t* Uh_f = wb + 98304;
  half_t* t1 = (half_t*)((char*)d_ws + (1<<20));     // 100000*128 f16 = 25.6 MB
  half_t* hA = t1 + (size_t)NV*128;                  // pair-interleaved
  half_t* hB = hA + (size_t)(NTOK/2)*128;

  bias_k<<<1, 384, 0, stream>>>(bWz,bUzl,bUzr,bWr,bUrl,bUrr,bWh,bUhl,bUhr, bc);
  wprep_k<<<512, 256, 0, stream>>>(Wz,Wh,Uzl,Uzr,Url,Urr,Uhl,Uhr, wb);

  h1tab_k<4><<<(NV + 63)/64, 512, 0, stream>>>(emb, Wz_f, Wh_f, bc, t1);

  float* outf = (float*)d_out;
  // grid: 256 persistent-ish blocks; tpb tiles (32 rows) each
  tree_k<1,0><<<256, 768, 0, stream>>>(t1, tokens, (uint*)hA, outf, Uz_f, Ur_f, Uh_f, bc, 16); // L1 131072
  tree_k<0,0><<<256, 768, 0, stream>>>(hA, tokens, (uint*)hB, outf, Uz_f, Ur_f, Uh_f, bc, 8);  // L2 65536
  tree_k<0,0><<<256, 768, 0, stream>>>(hB, tokens, (uint*)hA, outf, Uz_f, Ur_f, Uh_f, bc, 4);  // L3 32768
  tree_k<0,0><<<256, 768, 0, stream>>>(hA, tokens, (uint*)hB, outf, Uz_f, Ur_f, Uh_f, bc, 2);  // L4 16384
  tree_k<0,0><<<256, 768, 0, stream>>>(hB, tokens, (uint*)hA, outf, Uz_f, Ur_f, Uh_f, bc, 1);  // L5 8192
  tree_k<0,1><<<128, 768, 0, stream>>>(hA, tokens, (uint*)hB, outf, Uz_f, Ur_f, Uh_f, bc, 1);  // L6 4096 -> f32
}

// Round 17
// 135.806 us; speedup vs baseline: 1.5165x; 1.5165x over previous
//
#include <hip/hip_runtime.h>

// EncoderTreeRNN — R17: R8 pipeline (best, 149.8) + FUSED L2..L6 kernel (in-LDS level chain)
// + bias folded into wprep. 16x16 MFMA path throughout (R8-verified layouts).
// Tree (word=0): z=sigm(hl Uzl+hr Uzr+bz), r=sigm(hl Url+hr Urr+br),
//                h~=tanh((r*hl)Uhl+(r*hr)Uhr+bh), out=z*(hl+hr)+(1-z)*h~
// K interleaved (k'=2j -> hl[j], 2j+1 -> hr[j]); U rows permuted to match.
// U frag (16x16): Uf[((w*8+ks)*64+l)*8+j] = U'[ks*32+(l>>4)*8+j][w*16+(l&15)].
// C/D (16x16): col=lane&15, row=(lane>>4)*4+q.

typedef _Float16 half_t;
typedef __attribute__((ext_vector_type(2))) _Float16 f16x2;
typedef __attribute__((ext_vector_type(8))) _Float16 f16x8;
typedef __attribute__((ext_vector_type(4))) float f32x4;

#define NTOK 262144
#define NB 4096
#define NV 100000

__device__ __forceinline__ float sigm(float x){
  float e = __expf(-x);
  return __builtin_amdgcn_rcpf(1.0f + e);
}
__device__ __forceinline__ float tanh_(float x){
  float e = __expf(2.f*x);
  float r = __builtin_amdgcn_rcpf(1.0f + e);
  return __builtin_fmaf(-2.0f, r, 1.0f);
}

// Fragment-contiguous weights (R8 layout) + combined biases (block 511).
__global__ __launch_bounds__(256) void wprep_k(
    const float* Wz, const float* Wh,
    const float* Uzl,const float* Uzr,const float* Url,const float* Urr,
    const float* Uhl,const float* Uhr,
    const float* bWz,const float* bUzl,const float* bUzr,
    const float* bWr,const float* bUrl,const float* bUrr,
    const float* bWh,const float* bUhl,const float* bUhr,
    half_t* wb, float* bc){
  int idx = blockIdx.x*256 + threadIdx.x;           // 131072 total
  if (idx < 32768){                                  // Wz_f, Wh_f (16x16, K=128)
    const float* W = (idx < 16384) ? Wz : Wh;
    int t = idx & 16383;
    int w = t >> 11, ks = (t >> 9) & 3, l = (t >> 3) & 63, j = t & 7;
    int n = w*16 + (l & 15);
    int k = ks*32 + ((l >> 4) << 3) + j;
    wb[idx] = (half_t)W[k*128 + n];
  } else {                                           // Uz_f, Ur_f, Uh_f (16x16, K=256 interleaved)
    int t = idx - 32768;
    int mat = t >> 15;                               // 0=z,1=r,2=h
    t &= 32767;
    int w = t >> 12, ks = (t >> 9) & 7, l = (t >> 3) & 63, j = t & 7;
    int n = w*16 + (l & 15);
    int kp = ks*32 + ((l >> 4) << 3) + j;            // 0..255 interleaved
    int k = kp >> 1;
    const float* U;
    if (mat == 0) U = (kp & 1) ? Uzr : Uzl;
    else if (mat == 1) U = (kp & 1) ? Urr : Url;
    else U = (kp & 1) ? Uhr : Uhl;
    wb[idx] = (half_t)U[k*128 + n];
  }
  if (blockIdx.x == 511 && threadIdx.x < 128){
    int j = threadIdx.x;
    bc[j]       = bWz[j] + bUzl[j] + bUzr[j];
    bc[128 + j] = bWr[j] + bUrl[j] + bUrr[j];
    bc[256 + j] = bWh[j] + bUhl[j] + bUhr[j];
  }
}

// Vocab table: t1[v] = (1-z)*tanh(xWh+bh), z=sigm(xWz+bz). Sequential rows.
template<int MT>
__global__ __launch_bounds__(512, 8) void h1tab_k(
    const float* __restrict__ emb,
    const half_t* __restrict__ Wz_f, const half_t* __restrict__ Wh_f,
    const float* __restrict__ bc, half_t* __restrict__ t1)
{
  __shared__ __align__(16) _Float16 xs[MT*16][136];
  const int tid = threadIdx.x;
  const int m0  = blockIdx.x*(MT*16);
  #pragma unroll
  for (int it = 0; it < MT; it++){
    int idx = it*512 + tid;
    int m = idx >> 5, c = idx & 31;
    int row = m0 + m; if (row >= NV) row = 0;
    float4 v = ((const float4*)(emb + (size_t)row*128))[c];
    union { half_t h[4]; ushort4 u; } p;
    p.h[0]=(half_t)v.x; p.h[1]=(half_t)v.y; p.h[2]=(half_t)v.z; p.h[3]=(half_t)v.w;
    *(ushort4*)&xs[m][c*4] = p.u;
  }
  __syncthreads();
  const int w = tid>>6, l = tid&63;
  const int lr = l&15, lk = (l>>4)*8, lq = (l>>4)*4;
  const int col = w*16 + lr;

  f32x4 zacc[MT] = {}; f32x4 hacc[MT] = {};
  const half_t* wzp = Wz_f + ((w*4)*64 + l)*8;
  const half_t* whp = Wh_f + ((w*4)*64 + l)*8;
  #pragma unroll
  for (int ks=0; ks<4; ks++){
    f16x8 bz = *(const f16x8*)(wzp + ks*512);
    f16x8 bh = *(const f16x8*)(whp + ks*512);
    #pragma unroll
    for (int mt=0; mt<MT; mt++){
      f16x8 a = *(const f16x8*)&xs[mt*16 + lr][ks*32 + lk];
      zacc[mt] = __builtin_amdgcn_mfma_f32_16x16x32_f16(a, bz, zacc[mt],0,0,0);
      hacc[mt] = __builtin_amdgcn_mfma_f32_16x16x32_f16(a, bh, hacc[mt],0,0,0);
    }
  }
  const float bzv = bc[col], bhv = bc[256+col];
  #pragma unroll
  for (int mt=0; mt<MT; mt++){
    #pragma unroll
    for (int q=0; q<4; q++){
      int row = m0 + mt*16 + lq + q;
      if (row < NV){
        float z  = sigm(zacc[mt][q] + bzv);
        float ht = tanh_(hacc[mt][q] + bhv);
        t1[(size_t)row*128 + col] = (half_t)((1.f-z)*ht);
      }
    }
  }
}

// L1 (R8-exact): gather from t1 via tokens, MT=8, 512 thr, 8 waves x 16 cols.
template<int MT>
__global__ __launch_bounds__(512, 4) void tree1_k(
    const half_t* __restrict__ hin, const int* __restrict__ tokens,
    half_t* __restrict__ hout,
    const half_t* __restrict__ Uz_f, const half_t* __restrict__ Ur_f, const half_t* __restrict__ Uh_f,
    const float* __restrict__ bc)
{
  __shared__ __align__(16) _Float16 xs[MT*16][264];
  const int tid = threadIdx.x;
  const int m0  = blockIdx.x*(MT*16);
  #pragma unroll
  for (int it = 0; it < MT; it++){
    int idx = it*512 + tid;
    int m = idx >> 5, c = idx & 31;
    int tl = tokens[2*(m0+m)], tr = tokens[2*(m0+m)+1];
    uint2 A  = *(const uint2*)(hin + (size_t)tl*128 + c*4);
    uint2 Bv = *(const uint2*)(hin + (size_t)tr*128 + c*4);
    uint4 o;
    o.x = (A.x & 0xFFFFu) | (Bv.x << 16);
    o.y = (A.x >> 16)     | (Bv.x & 0xFFFF0000u);
    o.z = (A.y & 0xFFFFu) | (Bv.y << 16);
    o.w = (A.y >> 16)     | (Bv.y & 0xFFFF0000u);
    *(uint4*)&xs[m][c*8] = o;
  }
  __syncthreads();
  const int w = tid>>6, l = tid&63;
  const int lr = l&15, lk = (l>>4)*8, lq = (l>>4)*4;
  const int col = w*16 + lr;

  f32x4 zacc[MT] = {}, racc[MT] = {};
  const half_t* uzp = Uz_f + ((w*8)*64 + l)*8;
  const half_t* urp = Ur_f + ((w*8)*64 + l)*8;
  f16x8 bz_n = *(const f16x8*)uzp;
  f16x8 br_n = *(const f16x8*)urp;
  #pragma unroll
  for (int ks=0; ks<8; ks++){
    f16x8 bz = bz_n, br = br_n;
    if (ks < 7){
      bz_n = *(const f16x8*)(uzp + (ks+1)*512);
      br_n = *(const f16x8*)(urp + (ks+1)*512);
    }
    #pragma unroll
    for (int mt=0; mt<MT; mt++){
      f16x8 a = *(const f16x8*)&xs[mt*16 + lr][ks*32 + lk];
      zacc[mt] = __builtin_amdgcn_mfma_f32_16x16x32_f16(a, bz, zacc[mt],0,0,0);
      racc[mt] = __builtin_amdgcn_mfma_f32_16x16x32_f16(a, br, racc[mt],0,0,0);
    }
  }
  __syncthreads();

  uint zp[MT][2], sp[MT][2];
  const float bzv = bc[col], brv = bc[128+col];
  #pragma unroll
  for (int mt=0; mt<MT; mt++){
    union { half_t h[4]; uint u[2]; } pz, ps;
    #pragma unroll
    for (int q=0; q<4; q++){
      int row = mt*16 + lq + q;
      union { uint u; half_t h[2]; } io;
      io.u = *(uint*)&xs[row][2*col];
      float hl = (float)io.h[0];
      float hr = (float)io.h[1];
      float z  = sigm(zacc[mt][q] + bzv);
      float rv = sigm(racc[mt][q] + brv);
      pz.h[q] = (half_t)z;
      ps.h[q] = (half_t)(hl + hr);
      io.h[0] = (half_t)(rv*hl);
      io.h[1] = (half_t)(rv*hr);
      *(uint*)&xs[row][2*col] = io.u;
    }
    zp[mt][0]=pz.u[0]; zp[mt][1]=pz.u[1];
    sp[mt][0]=ps.u[0]; sp[mt][1]=ps.u[1];
  }
  __syncthreads();

  f32x4 ha[MT] = {};
  const half_t* uhp = Uh_f + ((w*8)*64 + l)*8;
  f16x8 bh_n = *(const f16x8*)uhp;
  #pragma unroll
  for (int ks=0; ks<8; ks++){
    f16x8 bh = bh_n;
    if (ks < 7) bh_n = *(const f16x8*)(uhp + (ks+1)*512);
    #pragma unroll
    for (int mt=0; mt<MT; mt++){
      f16x8 a = *(const f16x8*)&xs[mt*16 + lr][ks*32 + lk];
      ha[mt] = __builtin_amdgcn_mfma_f32_16x16x32_f16(a, bh, ha[mt],0,0,0);
    }
  }
  const float bhv = bc[256+col];
  #pragma unroll
  for (int mt=0; mt<MT; mt++){
    union { half_t h[4]; uint u[2]; } pz, ps;
    pz.u[0]=zp[mt][0]; pz.u[1]=zp[mt][1];
    ps.u[0]=sp[mt][0]; ps.u[1]=sp[mt][1];
    #pragma unroll
    for (int q=0; q<4; q++){
      int row = mt*16 + lq + q;
      float ht = tanh_(ha[mt][q] + bhv);
      float z  = (float)pz.h[q];
      float o  = z*(float)ps.h[q] + (1.f-z)*ht;
      hout[(size_t)(m0+row)*128 + col] = (half_t)o;
    }
  }
}

// One level inside the fused kernel. X: input slots (interleaved), Y: next-level input.
// RV = valid out rows (<= MT*16). LAST: write f32 to outf instead of Y.
template<int MT, int RV, int LAST>
static __device__ __forceinline__ void level_step(
    _Float16 (*X)[264], _Float16 (*Y)[264], int tid,
    const half_t* Uz_f, const half_t* Ur_f, const half_t* Uh_f,
    const float* bc, float* outf, int outrow0)
{
  const int w = tid>>6, l = tid&63;
  const int lr = l&15, lk = (l>>4)*8, lq = (l>>4)*4;
  const int col = w*16 + lr;

  f32x4 zacc[MT] = {}, racc[MT] = {};
  const half_t* uzp = Uz_f + ((w*8)*64 + l)*8;
  const half_t* urp = Ur_f + ((w*8)*64 + l)*8;
  #pragma unroll
  for (int ks=0; ks<8; ks++){
    f16x8 bz = *(const f16x8*)(uzp + ks*512);
    f16x8 br = *(const f16x8*)(urp + ks*512);
    #pragma unroll
    for (int mt=0; mt<MT; mt++){
      f16x8 a = *(const f16x8*)&X[mt*16 + lr][ks*32 + lk];
      zacc[mt] = __builtin_amdgcn_mfma_f32_16x16x32_f16(a, bz, zacc[mt],0,0,0);
      racc[mt] = __builtin_amdgcn_mfma_f32_16x16x32_f16(a, br, racc[mt],0,0,0);
    }
  }
  __syncthreads();

  uint zp[MT][2], sp[MT][2];
  const float bzv = bc[col], brv = bc[128+col];
  #pragma unroll
  for (int mt=0; mt<MT; mt++){
    union { half_t h[4]; uint u[2]; } pz, ps;
    #pragma unroll
    for (int q=0; q<4; q++){
      int row = mt*16 + lq + q;
      union { uint u; half_t h[2]; } io;
      io.u = *(uint*)&X[row][2*col];
      float hl = (float)io.h[0];
      float hr = (float)io.h[1];
      float z  = sigm(zacc[mt][q] + bzv);
      float rv = sigm(racc[mt][q] + brv);
      pz.h[q] = (half_t)z;
      ps.h[q] = (half_t)(hl + hr);
      io.h[0] = (half_t)(rv*hl);
      io.h[1] = (half_t)(rv*hr);
      *(uint*)&X[row][2*col] = io.u;
    }
    zp[mt][0]=pz.u[0]; zp[mt][1]=pz.u[1];
    sp[mt][0]=ps.u[0]; sp[mt][1]=ps.u[1];
  }
  __syncthreads();

  f32x4 ha[MT] = {};
  const half_t* uhp = Uh_f + ((w*8)*64 + l)*8;
  #pragma unroll
  for (int ks=0; ks<8; ks++){
    f16x8 bh = *(const f16x8*)(uhp + ks*512);
    #pragma unroll
    for (int mt=0; mt<MT; mt++){
      f16x8 a = *(const f16x8*)&X[mt*16 + lr][ks*32 + lk];
      ha[mt] = __builtin_amdgcn_mfma_f32_16x16x32_f16(a, bh, ha[mt],0,0,0);
    }
  }
  const float bhv = bc[256+col];
  #pragma unroll
  for (int mt=0; mt<MT; mt++){
    union { half_t h[4]; uint u[2]; } pz, ps;
    pz.u[0]=zp[mt][0]; pz.u[1]=zp[mt][1];
    ps.u[0]=sp[mt][0]; ps.u[1]=sp[mt][1];
    #pragma unroll
    for (int q=0; q<4; q++){
      int row = mt*16 + lq + q;
      if (row < RV){
        float ht = tanh_(ha[mt][q] + bhv);
        float z  = (float)pz.h[q];
        float o  = z*(float)ps.h[q] + (1.f-z)*ht;
        if (LAST) outf[(size_t)(outrow0 + row)*128 + col] = o;
        else      Y[row>>1][2*col + (row&1)] = (half_t)o;
      }
    }
  }
  __syncthreads();
}

// Fused L2..L6: block = 4 batches (128 contiguous hA rows), all levels in LDS.
__global__ __launch_bounds__(512, 6) void tree_tail_k(
    const half_t* __restrict__ hA, float* __restrict__ outf,
    const half_t* __restrict__ Uz_f, const half_t* __restrict__ Ur_f, const half_t* __restrict__ Uh_f,
    const float* __restrict__ bc)
{
  __shared__ __align__(16) _Float16 XA[64][264];   // 33.8 KB
  __shared__ __align__(16) _Float16 XB[32][264];   // 16.9 KB
  const int tid = threadIdx.x;
  const int g = blockIdx.x;                        // batches 4g..4g+3
  // stage: L2 input slots m=0..63: b=m>>4, i=m&15 -> hA rows 128g + b*32 + 2i, +1
  #pragma unroll
  for (int it = 0; it < 4; it++){
    int idx = it*512 + tid;
    int m = idx >> 5, c = idx & 31;
    int b = m >> 4, i = m & 15;
    size_t base = ((size_t)(128*g + b*32 + 2*i))*128 + c*4;
    uint2 A  = *(const uint2*)(hA + base);
    uint2 Bv = *(const uint2*)(hA + base + 128);
    uint4 o;
    o.x = (A.x & 0xFFFFu) | (Bv.x << 16);
    o.y = (A.x >> 16)     | (Bv.x & 0xFFFF0000u);
    o.z = (A.y & 0xFFFFu) | (Bv.y << 16);
    o.w = (A.y >> 16)     | (Bv.y & 0xFFFF0000u);
    *(uint4*)&XA[m][c*8] = o;
  }
  __syncthreads();
  level_step<4,64,0>(XA, XB, tid, Uz_f, Ur_f, Uh_f, bc, outf, 0);   // L2: 64 out
  level_step<2,32,0>(XB, XA, tid, Uz_f, Ur_f, Uh_f, bc, outf, 0);   // L3: 32 out
  level_step<1,16,0>(XA, XB, tid, Uz_f, Ur_f, Uh_f, bc, outf, 0);   // L4: 16 out
  level_step<1, 8,0>(XB, XA, tid, Uz_f, Ur_f, Uh_f, bc, outf, 0);   // L5: 8 out
  level_step<1, 4,1>(XA, XB, tid, Uz_f, Ur_f, Uh_f, bc, outf, 4*g); // L6: 4 out -> f32
}

extern "C" void kernel_launch(void* const* d_in, const int* in_sizes, int n_in,
                              void* d_out, int out_size, void* d_ws, size_t ws_size,
                              hipStream_t stream) {
  const int*   tokens = (const int*)  d_in[0];
  const float* emb    = (const float*)d_in[1];
  const float* Wz  = (const float*)d_in[2];  const float* bWz  = (const float*)d_in[3];
  const float* Uzl = (const float*)d_in[4];  const float* bUzl = (const float*)d_in[5];
  const float* Uzr = (const float*)d_in[6];  const float* bUzr = (const float*)d_in[7];
  const float* Wr  = (const float*)d_in[8];  const float* bWr  = (const float*)d_in[9];
  const float* Url = (const float*)d_in[10]; const float* bUrl = (const float*)d_in[11];
  const float* Urr = (const float*)d_in[12]; const float* bUrr = (const float*)d_in[13];
  const float* Wh  = (const float*)d_in[14]; const float* bWh  = (const float*)d_in[15];
  const float* Uhl = (const float*)d_in[16]; const float* bUhl = (const float*)d_in[17];
  const float* Uhr = (const float*)d_in[18]; const float* bUhr = (const float*)d_in[19];

  float*  bc = (float*)d_ws;
  half_t* wb = (half_t*)((char*)d_ws + 4096);
  half_t* Wz_f = wb;
  half_t* Wh_f = wb + 16384;
  half_t* Uz_f = wb + 32768;
  half_t* Ur_f = wb + 65536;
  half_t* Uh_f = wb + 98304;
  half_t* t1 = (half_t*)((char*)d_ws + (1<<20));     // 100000*128 f16 = 25.6 MB
  half_t* hA = t1 + (size_t)NV*128;                  // 131072*128 f16 = 33.5 MB

  wprep_k<<<512, 256, 0, stream>>>(Wz,Wh,Uzl,Uzr,Url,Urr,Uhl,Uhr,
                                   bWz,bUzl,bUzr,bWr,bUrl,bUrr,bWh,bUhl,bUhr, wb, bc);

  h1tab_k<4><<<(NV + 63)/64, 512, 0, stream>>>(emb, Wz_f, Wh_f, bc, t1);

  // L1: gather from t1 via tokens -> hA (row-major f16), M=131072
  tree1_k<8><<<(NTOK/2)/128, 512, 0, stream>>>(t1, tokens, hA, Uz_f, Ur_f, Uh_f, bc);

  // L2..L6 fused: 1024 blocks x 4 batches
  tree_tail_k<<<1024, 512, 0, stream>>>(hA, (float*)d_out, Uz_f, Ur_f, Uh_f, bc);
}

// Round 18
// 133.725 us; speedup vs baseline: 1.5401x; 1.0156x over previous
//
#include <hip/hip_runtime.h>

// EncoderTreeRNN — R18: FULL tree fusion (L1..L6 in one kernel). Block g owns batches
// 4g..4g+3: gathers its 256 tokens' t1 rows (2 chunks x 64 L1-out-rows), runs L1 via
// level_step into pair-interleaved L2 slots, then chains L2..L6 in LDS (R17-proven).
// No hA buffer: saves 61MB write + 47MB read + a dispatch boundary.
// Tree (word=0): z=sigm(hl Uzl+hr Uzr+bz), r=sigm(hl Url+hr Urr+br),
//                h~=tanh((r*hl)Uhl+(r*hr)Uhr+bh), out=z*(hl+hr)+(1-z)*h~
// K interleaved (k'=2j -> hl[j], 2j+1 -> hr[j]); U rows permuted to match.
// U frag (16x16): Uf[((w*8+ks)*64+l)*8+j] = U'[ks*32+(l>>4)*8+j][w*16+(l&15)].
// C/D (16x16): col=lane&15, row=(lane>>4)*4+q.

typedef _Float16 half_t;
typedef __attribute__((ext_vector_type(8))) _Float16 f16x8;
typedef __attribute__((ext_vector_type(4))) float f32x4;

#define NTOK 262144
#define NB 4096
#define NV 100000

__device__ __forceinline__ float sigm(float x){
  float e = __expf(-x);
  return __builtin_amdgcn_rcpf(1.0f + e);
}
__device__ __forceinline__ float tanh_(float x){
  float e = __expf(2.f*x);
  float r = __builtin_amdgcn_rcpf(1.0f + e);
  return __builtin_fmaf(-2.0f, r, 1.0f);
}

// Fragment-contiguous weights (R8/R17 layout) + combined biases (block 511).
__global__ __launch_bounds__(256) void wprep_k(
    const float* Wz, const float* Wh,
    const float* Uzl,const float* Uzr,const float* Url,const float* Urr,
    const float* Uhl,const float* Uhr,
    const float* bWz,const float* bUzl,const float* bUzr,
    const float* bWr,const float* bUrl,const float* bUrr,
    const float* bWh,const float* bUhl,const float* bUhr,
    half_t* wb, float* bc){
  int idx = blockIdx.x*256 + threadIdx.x;           // 131072 total
  if (idx < 32768){                                  // Wz_f, Wh_f (16x16, K=128)
    const float* W = (idx < 16384) ? Wz : Wh;
    int t = idx & 16383;
    int w = t >> 11, ks = (t >> 9) & 3, l = (t >> 3) & 63, j = t & 7;
    int n = w*16 + (l & 15);
    int k = ks*32 + ((l >> 4) << 3) + j;
    wb[idx] = (half_t)W[k*128 + n];
  } else {                                           // Uz_f, Ur_f, Uh_f (16x16, K=256 interleaved)
    int t = idx - 32768;
    int mat = t >> 15;                               // 0=z,1=r,2=h
    t &= 32767;
    int w = t >> 12, ks = (t >> 9) & 7, l = (t >> 3) & 63, j = t & 7;
    int n = w*16 + (l & 15);
    int kp = ks*32 + ((l >> 4) << 3) + j;            // 0..255 interleaved
    int k = kp >> 1;
    const float* U;
    if (mat == 0) U = (kp & 1) ? Uzr : Uzl;
    else if (mat == 1) U = (kp & 1) ? Urr : Url;
    else U = (kp & 1) ? Uhr : Uhl;
    wb[idx] = (half_t)U[k*128 + n];
  }
  if (blockIdx.x == 511 && threadIdx.x < 128){
    int j = threadIdx.x;
    bc[j]       = bWz[j] + bUzl[j] + bUzr[j];
    bc[128 + j] = bWr[j] + bUrl[j] + bUrr[j];
    bc[256 + j] = bWh[j] + bUhl[j] + bUhr[j];
  }
}

// Vocab table: t1[v] = (1-z)*tanh(xWh+bh), z=sigm(xWz+bz). Sequential rows.
template<int MT>
__global__ __launch_bounds__(512, 8) void h1tab_k(
    const float* __restrict__ emb,
    const half_t* __restrict__ Wz_f, const half_t* __restrict__ Wh_f,
    const float* __restrict__ bc, half_t* __restrict__ t1)
{
  __shared__ __align__(16) _Float16 xs[MT*16][136];
  const int tid = threadIdx.x;
  const int m0  = blockIdx.x*(MT*16);
  #pragma unroll
  for (int it = 0; it < MT; it++){
    int idx = it*512 + tid;
    int m = idx >> 5, c = idx & 31;
    int row = m0 + m; if (row >= NV) row = 0;
    float4 v = ((const float4*)(emb + (size_t)row*128))[c];
    union { half_t h[4]; ushort4 u; } p;
    p.h[0]=(half_t)v.x; p.h[1]=(half_t)v.y; p.h[2]=(half_t)v.z; p.h[3]=(half_t)v.w;
    *(ushort4*)&xs[m][c*4] = p.u;
  }
  __syncthreads();
  const int w = tid>>6, l = tid&63;
  const int lr = l&15, lk = (l>>4)*8, lq = (l>>4)*4;
  const int col = w*16 + lr;

  f32x4 zacc[MT] = {}; f32x4 hacc[MT] = {};
  const half_t* wzp = Wz_f + ((w*4)*64 + l)*8;
  const half_t* whp = Wh_f + ((w*4)*64 + l)*8;
  #pragma unroll
  for (int ks=0; ks<4; ks++){
    f16x8 bz = *(const f16x8*)(wzp + ks*512);
    f16x8 bh = *(const f16x8*)(whp + ks*512);
    #pragma unroll
    for (int mt=0; mt<MT; mt++){
      f16x8 a = *(const f16x8*)&xs[mt*16 + lr][ks*32 + lk];
      zacc[mt] = __builtin_amdgcn_mfma_f32_16x16x32_f16(a, bz, zacc[mt],0,0,0);
      hacc[mt] = __builtin_amdgcn_mfma_f32_16x16x32_f16(a, bh, hacc[mt],0,0,0);
    }
  }
  const float bzv = bc[col], bhv = bc[256+col];
  #pragma unroll
  for (int mt=0; mt<MT; mt++){
    #pragma unroll
    for (int q=0; q<4; q++){
      int row = m0 + mt*16 + lq + q;
      if (row < NV){
        float z  = sigm(zacc[mt][q] + bzv);
        float ht = tanh_(hacc[mt][q] + bhv);
        t1[(size_t)row*128 + col] = (half_t)((1.f-z)*ht);
      }
    }
  }
}

// One tree level on LDS. X: input slots (interleaved {hl,hr}), Y: next-level input slots.
// RV = valid out rows (<= MT*16); slot0 = Y slot offset; LAST: write f32 to outf.
template<int MT, int RV, int LAST>
static __device__ __forceinline__ void level_step(
    _Float16 (*X)[264], _Float16 (*Y)[264], int tid,
    const half_t* Uz_f, const half_t* Ur_f, const half_t* Uh_f,
    const float* bc, float* outf, int outrow0, int slot0)
{
  const int w = tid>>6, l = tid&63;
  const int lr = l&15, lk = (l>>4)*8, lq = (l>>4)*4;
  const int col = w*16 + lr;

  f32x4 zacc[MT] = {}, racc[MT] = {};
  const half_t* uzp = Uz_f + ((w*8)*64 + l)*8;
  const half_t* urp = Ur_f + ((w*8)*64 + l)*8;
  #pragma unroll
  for (int ks=0; ks<8; ks++){
    f16x8 bz = *(const f16x8*)(uzp + ks*512);
    f16x8 br = *(const f16x8*)(urp + ks*512);
    #pragma unroll
    for (int mt=0; mt<MT; mt++){
      f16x8 a = *(const f16x8*)&X[mt*16 + lr][ks*32 + lk];
      zacc[mt] = __builtin_amdgcn_mfma_f32_16x16x32_f16(a, bz, zacc[mt],0,0,0);
      racc[mt] = __builtin_amdgcn_mfma_f32_16x16x32_f16(a, br, racc[mt],0,0,0);
    }
  }
  __syncthreads();

  uint zp[MT][2], sp[MT][2];
  const float bzv = bc[col], brv = bc[128+col];
  #pragma unroll
  for (int mt=0; mt<MT; mt++){
    union { half_t h[4]; uint u[2]; } pz, ps;
    #pragma unroll
    for (int q=0; q<4; q++){
      int row = mt*16 + lq + q;
      union { uint u; half_t h[2]; } io;
      io.u = *(uint*)&X[row][2*col];
      float hl = (float)io.h[0];
      float hr = (float)io.h[1];
      float z  = sigm(zacc[mt][q] + bzv);
      float rv = sigm(racc[mt][q] + brv);
      pz.h[q] = (half_t)z;
      ps.h[q] = (half_t)(hl + hr);
      io.h[0] = (half_t)(rv*hl);
      io.h[1] = (half_t)(rv*hr);
      *(uint*)&X[row][2*col] = io.u;
    }
    zp[mt][0]=pz.u[0]; zp[mt][1]=pz.u[1];
    sp[mt][0]=ps.u[0]; sp[mt][1]=ps.u[1];
  }
  __syncthreads();

  f32x4 ha[MT] = {};
  const half_t* uhp = Uh_f + ((w*8)*64 + l)*8;
  #pragma unroll
  for (int ks=0; ks<8; ks++){
    f16x8 bh = *(const f16x8*)(uhp + ks*512);
    #pragma unroll
    for (int mt=0; mt<MT; mt++){
      f16x8 a = *(const f16x8*)&X[mt*16 + lr][ks*32 + lk];
      ha[mt] = __builtin_amdgcn_mfma_f32_16x16x32_f16(a, bh, ha[mt],0,0,0);
    }
  }
  const float bhv = bc[256+col];
  #pragma unroll
  for (int mt=0; mt<MT; mt++){
    union { half_t h[4]; uint u[2]; } pz, ps;
    pz.u[0]=zp[mt][0]; pz.u[1]=zp[mt][1];
    ps.u[0]=sp[mt][0]; ps.u[1]=sp[mt][1];
    #pragma unroll
    for (int q=0; q<4; q++){
      int row = mt*16 + lq + q;
      if (row < RV){
        float ht = tanh_(ha[mt][q] + bhv);
        float z  = (float)pz.h[q];
        float o  = z*(float)ps.h[q] + (1.f-z)*ht;
        if (LAST) outf[(size_t)(outrow0 + row)*128 + col] = o;
        else      Y[slot0 + (row>>1)][2*col + (row&1)] = (half_t)o;
      }
    }
  }
  __syncthreads();
}

// Fused L1..L6: block g = batches 4g..4g+3 (tokens 256g..256g+255, L1 out rows 128g..+127).
__global__ __launch_bounds__(512, 2) void fused_k(
    const half_t* __restrict__ t1, const int* __restrict__ tokens,
    float* __restrict__ outf,
    const half_t* __restrict__ Uz_f, const half_t* __restrict__ Ur_f, const half_t* __restrict__ Uh_f,
    const float* __restrict__ bc)
{
  __shared__ __align__(16) _Float16 XA[64][264];   // 33.8 KB
  __shared__ __align__(16) _Float16 XB[64][264];   // 33.8 KB
  const int tid = threadIdx.x;
  const int g = blockIdx.x;

  // ---- L1 in two chunks of 64 out-rows; results -> XB slots [32k .. 32k+31] ----
  #pragma unroll
  for (int k = 0; k < 2; k++){
    #pragma unroll
    for (int it = 0; it < 4; it++){
      int idx = it*512 + tid;           // 64 rows x 32 chunks
      int m = idx >> 5, c = idx & 31;
      int gm = 128*g + 64*k + m;        // global L1 out row
      int tl = tokens[2*gm], tr = tokens[2*gm+1];
      uint2 A  = *(const uint2*)(t1 + (size_t)tl*128 + c*4);
      uint2 Bv = *(const uint2*)(t1 + (size_t)tr*128 + c*4);
      uint4 o;
      o.x = (A.x & 0xFFFFu) | (Bv.x << 16);
      o.y = (A.x >> 16)     | (Bv.x & 0xFFFF0000u);
      o.z = (A.y & 0xFFFFu) | (Bv.y << 16);
      o.w = (A.y >> 16)     | (Bv.y & 0xFFFF0000u);
      *(uint4*)&XA[m][c*8] = o;
    }
    __syncthreads();
    level_step<4,64,0>(XA, XB, tid, Uz_f, Ur_f, Uh_f, bc, outf, 0, 32*k);
  }

  // ---- L2..L6 in LDS (R17-proven chain, one level deeper naming) ----
  level_step<4,64,0>(XB, XA, tid, Uz_f, Ur_f, Uh_f, bc, outf, 0, 0);   // L2: 64 out -> XA 0..31
  level_step<2,32,0>(XA, XB, tid, Uz_f, Ur_f, Uh_f, bc, outf, 0, 0);   // L3: 32 out -> XB 0..15
  level_step<1,16,0>(XB, XA, tid, Uz_f, Ur_f, Uh_f, bc, outf, 0, 0);   // L4: 16 out -> XA 0..7
  level_step<1, 8,0>(XA, XB, tid, Uz_f, Ur_f, Uh_f, bc, outf, 0, 0);   // L5:  8 out -> XB 0..3
  level_step<1, 4,1>(XB, XA, tid, Uz_f, Ur_f, Uh_f, bc, outf, 4*g, 0); // L6:  4 out -> f32
}

extern "C" void kernel_launch(void* const* d_in, const int* in_sizes, int n_in,
                              void* d_out, int out_size, void* d_ws, size_t ws_size,
                              hipStream_t stream) {
  const int*   tokens = (const int*)  d_in[0];
  const float* emb    = (const float*)d_in[1];
  const float* Wz  = (const float*)d_in[2];  const float* bWz  = (const float*)d_in[3];
  const float* Uzl = (const float*)d_in[4];  const float* bUzl = (const float*)d_in[5];
  const float* Uzr = (const float*)d_in[6];  const float* bUzr = (const float*)d_in[7];
  const float* Wr  = (const float*)d_in[8];  const float* bWr  = (const float*)d_in[9];
  const float* Url = (const float*)d_in[10]; const float* bUrl = (const float*)d_in[11];
  const float* Urr = (const float*)d_in[12]; const float* bUrr = (const float*)d_in[13];
  const float* Wh  = (const float*)d_in[14]; const float* bWh  = (const float*)d_in[15];
  const float* Uhl = (const float*)d_in[16]; const float* bUhl = (const float*)d_in[17];
  const float* Uhr = (const float*)d_in[18]; const float* bUhr = (const float*)d_in[19];

  float*  bc = (float*)d_ws;
  half_t* wb = (half_t*)((char*)d_ws + 4096);
  half_t* Wz_f = wb;
  half_t* Wh_f = wb + 16384;
  half_t* Uz_f = wb + 32768;
  half_t* Ur_f = wb + 65536;
  half_t* Uh_f = wb + 98304;
  half_t* t1 = (half_t*)((char*)d_ws + (1<<20));     // 100000*128 f16 = 25.6 MB

  wprep_k<<<512, 256, 0, stream>>>(Wz,Wh,Uzl,Uzr,Url,Urr,Uhl,Uhr,
                                   bWz,bUzl,bUzr,bWr,bUrl,bUrr,bWh,bUhl,bUhr, wb, bc);

  h1tab_k<4><<<(NV + 63)/64, 512, 0, stream>>>(emb, Wz_f, Wh_f, bc, t1);

  // All 6 tree levels fused: 1024 blocks x 4 batches
  fused_k<<<1024, 512, 0, stream>>>(t1, tokens, (float*)d_out, Uz_f, Ur_f, Uh_f, bc);
}